// Round 13
// baseline (75.908 us; speedup 1.0000x reference)
//
#include <hip/hip_runtime.h>

#define B_ 64
#define L_ 512
#define H_ 512
#define CENTER 255

typedef float  f32x4  __attribute__((ext_vector_type(4)));
typedef _Float16 f16x8 __attribute__((ext_vector_type(8)));
typedef unsigned short u16x4 __attribute__((ext_vector_type(4)));
typedef unsigned short u16x8 __attribute__((ext_vector_type(8)));
typedef unsigned short USH;

// ws layout (floats):
//   (free)    [0,      32768)
//   dec_feat [32768,  65536)
//   cov_feat [65536,  98304)
//   spart    [98304,  163840)   float[2][32768]: per-N-half partial scores
//   Bpk     [360448,  491520)   ushort[512][512]: fp16(attn_w) bits (row-major n,k)
//   Enc16  [1048576, 9437184)   ushort[32768][512]: fp16(enc) bits (row-major)

__device__ __forceinline__ float fast_tanh(float x) {
    float e = __expf(2.0f * x);
    return 1.0f - 2.0f * __builtin_amdgcn_rcpf(e + 1.0f);
}

// ================= pre v4: R8 roles + enc fp32->fp16 pack (96 MB stream) ================
__launch_bounds__(512)
__global__ void pre_kernel(const float* __restrict__ cvg_w, const float* __restrict__ cvg_b,
                           const float* __restrict__ coverage,
                           const float* __restrict__ aw, USH* __restrict__ bh16,
                           const float* __restrict__ enc, USH* __restrict__ enc16,
                           const float* __restrict__ hidden, const float* __restrict__ dec_w,
                           const float* __restrict__ dec_b,
                           float* __restrict__ dec_feat, float* __restrict__ cov_feat) {
    __shared__ float wl2[1024];            // w_eff rows for i0, i1
    __shared__ float cs[512 * 65];         // [j][c] coverage transposed, pad 65
    __shared__ float sbuf[512];
    __shared__ float pr[512];
    const int bid = blockIdx.x, t = threadIdx.x;
    const int i0 = bid, i1 = bid + 256;

    wl2[t]       = cvg_w[((size_t)(i0 * L_ + t)) * H_ + CENTER];
    wl2[512 + t] = cvg_w[((size_t)(i1 * L_ + t)) * H_ + CENTER];

    if (t < 256) {
        int i = bid * 256 + t;
        float4 x = *(const float4*)&aw[(size_t)i * 4];
        float xs[4] = {x.x, x.y, x.z, x.w};
        u16x4 h;
        #pragma unroll
        for (int j = 0; j < 4; ++j)
            h[j] = __builtin_bit_cast(USH, (_Float16)xs[j]);
        *(u16x4*)&bh16[(size_t)i * 4] = h;
    }

    // P1b: enc fp32 -> fp16 pack, row-major, fully coalesced (same cast as old in-kernel
    // CVT -> bit-identical GEMM inputs). 256 blocks x 512 thr x 32 float4 = 64 MB read.
    {
        const float4* e4 = (const float4*)enc;
        u16x4* o4 = (u16x4*)enc16;
        #pragma unroll 4
        for (int k = 0; k < 32; ++k) {
            int idx = bid * 16384 + k * 512 + t;
            float4 x = e4[idx];
            float xs[4] = {x.x, x.y, x.z, x.w};
            u16x4 h;
            #pragma unroll
            for (int j = 0; j < 4; ++j)
                h[j] = __builtin_bit_cast(USH, (_Float16)xs[j]);
            o4[idx] = h;
        }
    }

    const int b = bid >> 2, qq = bid & 3;
    const int ol = t & 127, part = t >> 7;
    sbuf[t] = hidden[b * H_ + t];
    __syncthreads();

    {
        const float* row  = dec_w + (size_t)(qq * 128 + ol) * H_ + part * 128;
        const float* hseg = sbuf + part * 128;
        float d0 = 0.f, d1 = 0.f, d2 = 0.f, d3 = 0.f;
        #pragma unroll
        for (int k = 0; k < 128; k += 16) {
            float4 w0 = *(const float4*)&row[k];
            float4 w1 = *(const float4*)&row[k + 4];
            float4 w2 = *(const float4*)&row[k + 8];
            float4 w3 = *(const float4*)&row[k + 12];
            d0 += w0.x * hseg[k]      + w0.y * hseg[k + 1]  + w0.z * hseg[k + 2]  + w0.w * hseg[k + 3];
            d1 += w1.x * hseg[k + 4]  + w1.y * hseg[k + 5]  + w1.z * hseg[k + 6]  + w1.w * hseg[k + 7];
            d2 += w2.x * hseg[k + 8]  + w2.y * hseg[k + 9]  + w2.z * hseg[k + 10] + w2.w * hseg[k + 11];
            d3 += w3.x * hseg[k + 12] + w3.y * hseg[k + 13] + w3.z * hseg[k + 14] + w3.w * hseg[k + 15];
        }
        pr[t] = d0 + d1 + d2 + d3;
    }

    #pragma unroll 8
    for (int c = 0; c < 64; ++c)
        cs[t * 65 + c] = coverage[c * L_ + t];
    __syncthreads();

    if (t < 128)
        dec_feat[b * H_ + qq * 128 + t] = pr[t] + pr[t + 128] + pr[t + 256] + pr[t + 384]
                                          + dec_b[qq * 128 + t];

    {
        const int bb = t >> 3, jg = t & 7;
        float s0 = 0.f, s1 = 0.f;
        #pragma unroll 8
        for (int jj = 0; jj < 64; ++jj) {
            int j = jg * 64 + ((jj + jg * 8) & 63);        // rotation: read 2/bank
            float c = cs[j * 65 + bb];
            s0 += c * wl2[j];
            s1 += c * wl2[512 + j];
        }
        s0 += __shfl_xor(s0, 1, 64);
        s0 += __shfl_xor(s0, 2, 64);
        s0 += __shfl_xor(s0, 4, 64);
        s1 += __shfl_xor(s1, 1, 64);
        s1 += __shfl_xor(s1, 2, 64);
        s1 += __shfl_xor(s1, 4, 64);
        if (jg == 0) {
            cov_feat[bb * L_ + i0] = s0 + cvg_b[i0];
            cov_feat[bb * L_ + i1] = s1 + cvg_b[i1];
        }
    }
}

// ================= fused MFMA GEMM (fp16) + tanh + dot(v) -> partial scores =============
// v8: PURE-ASYNC k-loop (m97+counted-vmcnt class). A is pre-packed fp16 (bit-identical
// values) and staged via global_load_lds like B: pre-swizzled per-lane SOURCE address
// (inverts the old awoff writer mapping: slot s -> x=(s&7)^((s>>3)&7), arow=2*(s>>3)+
// (x>>2), ak4=x&3), linear LDS dest, triple-buffered. k-loop has ZERO ds_writes, zero
// CVT VALU, no lgkmcnt drain at the barrier — only counted vmcnt(3) (3 VMEM/step).
// Fragment reads (aoff/boff), MFMA order, epilogue byte-identical to R8.
#define BM 128

#define STAGE_AB(BUF, KS1)                                                                 \
    {                                                                                      \
        _Pragma("unroll")                                                                  \
        for (int it = 0; it < 2; ++it)                                                     \
            __builtin_amdgcn_global_load_lds(                                              \
                (const __attribute__((address_space(1))) void*)(bh16 + goffB[it] + (KS1) * 32), \
                (__attribute__((address_space(3))) void*)&Bsh[BUF][(wv * 2 + it) * 512],   \
                16, 0, 0);                                                                 \
        __builtin_amdgcn_global_load_lds(                                                  \
            (const __attribute__((address_space(1))) void*)(enc16 + goffA + (KS1) * 32),   \
            (__attribute__((address_space(3))) void*)&Ash[BUF][wv * 512],                  \
            16, 0, 0);                                                                     \
    }

__launch_bounds__(512, 4)
__global__ void fused_score_mfma(const USH* __restrict__ enc16,
                                 const USH* __restrict__ bh16,
                                 const float* __restrict__ attn_b,
                                 const float* __restrict__ dec_feat,
                                 const float* __restrict__ cov_feat,
                                 const float* __restrict__ v,
                                 float* __restrict__ spart) {
    __shared__ USH Bsh[3][8192];       // [buf][256n x 32k swizzled fp16] = 48 KB
    __shared__ USH Ash[3][4096];       // [buf][128r x 32k swizzled fp16] = 24 KB

    const int t  = threadIdx.x;
    const int wv = t >> 6, ln = t & 63;
    const int wr = wv >> 2, wc = wv & 3;     // 2M x 4N, wave tile 64 x 64
    const int q  = ln >> 4, cl = ln & 15;
    const int mt = blockIdx.x, half = blockIdx.y;
    const int m0 = mt * BM;
    const int b  = mt >> 2;                  // 4 row-tiles per batch row
    const int n0 = half * 256;

    int goffB[2];
    #pragma unroll
    for (int it = 0; it < 2; ++it) {
        int c   = wv * 2 + it;               // 16 chunks cover 256 n
        int srl = ln >> 3;
        int u   = (ln & 7) ^ (srl & 7);
        int n   = n0 + c * 16 + srl * 2 + (u >> 2);
        goffB[it] = n * 512 + (u & 3) * 8;
    }
    // A staging source swizzle: lane covers Ash slot s = wv*64+ln (16B each).
    // x = (ln&7)^(ln>>3); arow = wv*16 + (ln>>3)*2 + (x>>2); ak4 = x&3.
    int goffA;
    {
        int x    = (ln & 7) ^ (ln >> 3);
        int arw  = wv * 16 + (ln >> 3) * 2 + (x >> 2);
        goffA = (m0 + arw) * 512 + (x & 3) * 8;
    }
    const int sA   = (((cl & 1) * 4 + q) ^ ((cl >> 1) & 7)) * 8;
    const int aoff = wr * 2048 + (cl >> 1) * 64 + sA;
    const int boff = wc * 2048 + (cl >> 1) * 64 + sA;

    f32x4 acc[4][4];
    #pragma unroll
    for (int mf = 0; mf < 4; ++mf)
        #pragma unroll
        for (int nf = 0; nf < 4; ++nf) acc[mf][nf] = (f32x4){0.f, 0.f, 0.f, 0.f};

    STAGE_AB(0, 0);
    STAGE_AB(1, 1);
    __builtin_amdgcn_sched_barrier(0);
    asm volatile("s_waitcnt vmcnt(3)" ::: "memory");     // buf0 resident; buf1 in flight
    __builtin_amdgcn_sched_barrier(0);
    __builtin_amdgcn_s_barrier();

    #pragma unroll
    for (int ks = 0; ks < 16; ++ks) {
        const int cur = ks % 3;
        if (ks < 14)
            STAGE_AB((ks + 2) % 3, ks + 2);
        __builtin_amdgcn_sched_barrier(0);

        f16x8 ah[4];
        #pragma unroll
        for (int mf = 0; mf < 4; ++mf)
            ah[mf] = *(const f16x8*)&Ash[cur][aoff + mf * 512];
        __builtin_amdgcn_s_setprio(1);
        #pragma unroll
        for (int nf = 0; nf < 4; ++nf) {
            f16x8 bh = *(const f16x8*)&Bsh[cur][boff + nf * 512];
            #pragma unroll
            for (int mf = 0; mf < 4; ++mf)
                acc[mf][nf] = __builtin_amdgcn_mfma_f32_16x16x32_f16(ah[mf], bh, acc[mf][nf], 0, 0, 0);
        }
        __builtin_amdgcn_s_setprio(0);

        if (ks < 15) {
            if (ks < 14)
                asm volatile("s_waitcnt vmcnt(3)" ::: "memory");   // drain stage(ks+1)
            else
                asm volatile("s_waitcnt vmcnt(0)" ::: "memory");   // drain stage(15)
            __builtin_amdgcn_sched_barrier(0);
            __builtin_amdgcn_s_barrier();
        }
    }
    __syncthreads();

    float (*scred)[BM] = (float (*)[BM])Ash;
    float addv[4], vvv[4];
    #pragma unroll
    for (int nf = 0; nf < 4; ++nf) {
        int n = n0 + wc * 64 + nf * 16 + cl;
        addv[nf] = attn_b[n] + dec_feat[b * H_ + n];
        vvv[nf]  = v[b * H_ + n];
    }
    #pragma unroll
    for (int mf = 0; mf < 4; ++mf) {
        #pragma unroll
        for (int reg = 0; reg < 4; ++reg) {
            int row = wr * 64 + mf * 16 + q * 4 + reg;
            float cf = cov_feat[m0 + row];
            float s = 0.f;
            #pragma unroll
            for (int nf = 0; nf < 4; ++nf)
                s += fast_tanh(acc[mf][nf][reg] + addv[nf] + cf) * vvv[nf];
            s += __shfl_xor(s, 1, 64);
            s += __shfl_xor(s, 2, 64);
            s += __shfl_xor(s, 4, 64);
            s += __shfl_xor(s, 8, 64);
            if (cl == 0) scred[wc][row] = s;
        }
    }
    __syncthreads();
    if (t < BM) {
        float s = 0.f;
        #pragma unroll
        for (int g = 0; g < 4; ++g) s += scred[g][t];
        spart[half * (B_ * L_) + m0 + t] = s;
    }
}

// ================= smctx: masked softmax + outputs + context ============================
// (byte-identical to R12.)
__launch_bounds__(1024)
__global__ void smctx_kernel(const float* __restrict__ spart, const int* __restrict__ mask,
                             const float* __restrict__ coverage, const float* __restrict__ enc,
                             float* __restrict__ out) {
    __shared__ float w[512];
    __shared__ float red[16];
    __shared__ float red2[16];
    __shared__ float4 cred4[32][32];   // 16 KB
    __shared__ float4 cmid[4][32];     // 2 KB
    const int bid = blockIdx.x, b = bid >> 2, hc = bid & 3, t = threadIdx.x;
    const int wv = t >> 6, ln = t & 63;

    float sv = 0.f; bool mk = false;
    if (t < 512) {
        mk = (mask[b * L_ + t] == 1);
        sv = spart[b * L_ + t] + spart[B_ * L_ + b * L_ + t];
    }
    float val = (t < 512 && mk) ? sv : -INFINITY;

    float r = val;
    #pragma unroll
    for (int d = 1; d <= 32; d <<= 1) r = fmaxf(r, __shfl_xor(r, d, 64));
    if (ln == 0) red[wv] = r;
    __syncthreads();
    float gmax = red[0];
    #pragma unroll
    for (int i = 1; i < 16; ++i) gmax = fmaxf(gmax, red[i]);

    float p = (t < 512 && mk) ? __expf(sv - gmax) : 0.f;
    float qq = p;
    #pragma unroll
    for (int d = 1; d <= 32; d <<= 1) qq += __shfl_xor(qq, d, 64);
    if (ln == 0) red2[wv] = qq;
    __syncthreads();
    float tot = 0.f;
    #pragma unroll
    for (int i = 0; i < 16; ++i) tot += red2[i];

    float wt = p / tot;
    if (t < 512) {
        w[t] = wt;
        if (hc == 0) {
            out[B_ * H_ + b * L_ + t] = wt;                                   // attn_weights
            out[B_ * H_ + B_ * L_ + b * L_ + t] = coverage[b * L_ + t] + wt;  // new_coverage
        }
    }
    __syncthreads();

    const int c4 = t & 31, rg = t >> 5;    // 32 row-groups x 32 float4 columns
    const float4* ebase = (const float4*)enc
                          + ((size_t)(b * L_ + rg)) * 128 + hc * 32 + c4;
    float4 a4 = {0.f, 0.f, 0.f, 0.f};
    #pragma unroll
    for (int k = 0; k < 16; ++k) {         // rows rg, rg+32, ..., rg+480
        float wl_ = w[rg + 32 * k];
        float4 e = ebase[(size_t)(32 * k) * 128];
        a4.x += wl_ * e.x; a4.y += wl_ * e.y; a4.z += wl_ * e.z; a4.w += wl_ * e.w;
    }
    cred4[rg][c4] = a4;
    __syncthreads();
    if (t < 128) {
        const int gq = t >> 5;
        float4 s = {0.f, 0.f, 0.f, 0.f};
        #pragma unroll
        for (int g = 0; g < 8; ++g) {
            float4 c = cred4[gq * 8 + g][c4];
            s.x += c.x; s.y += c.y; s.z += c.z; s.w += c.w;
        }
        cmid[gq][c4] = s;
    }
    __syncthreads();
    if (t < 32) {
        float4 s = {0.f, 0.f, 0.f, 0.f};
        #pragma unroll
        for (int g = 0; g < 4; ++g) {
            float4 c = cmid[g][t];
            s.x += c.x; s.y += c.y; s.z += c.z; s.w += c.w;
        }
        *(float4*)&out[b * H_ + hc * 128 + t * 4] = s;
    }
}

extern "C" void kernel_launch(void* const* d_in, const int* in_sizes, int n_in,
                              void* d_out, int out_size, void* d_ws, size_t ws_size,
                              hipStream_t stream) {
    const float* enc      = (const float*)d_in[0];
    const int*   mask     = (const int*)d_in[1];
    const float* hidden   = (const float*)d_in[2];
    const float* coverage = (const float*)d_in[3];
    const float* attn_w   = (const float*)d_in[4];
    const float* attn_b   = (const float*)d_in[5];
    const float* dec_w    = (const float*)d_in[6];
    const float* dec_b    = (const float*)d_in[7];
    const float* cvg_w    = (const float*)d_in[8];
    const float* cvg_b    = (const float*)d_in[9];
    const float* v        = (const float*)d_in[10];
    float* out = (float*)d_out;
    float* ws  = (float*)d_ws;
    float* dec_feat = ws + 32768;
    float* cov_feat = ws + 65536;
    float* spart    = ws + 98304;
    USH* bpk   = (USH*)(ws + 360448);
    USH* enc16 = (USH*)(ws + 1048576);

    hipLaunchKernelGGL(pre_kernel,       dim3(256),     dim3(512),  0, stream,
                       cvg_w, cvg_b, coverage, attn_w, bpk, enc, enc16, hidden,
                       dec_w, dec_b, dec_feat, cov_feat);
    hipLaunchKernelGGL(fused_score_mfma, dim3(256, 2),  dim3(512),  0, stream,
                       enc16, bpk, attn_b, dec_feat, cov_feat, v, spart);
    hipLaunchKernelGGL(smctx_kernel,     dim3(256),     dim3(1024), 0, stream,
                       spart, mask, coverage, enc, out);
}

// Round 14
// 64.677 us; speedup vs baseline: 1.1737x; 1.1737x over previous
//
#include <hip/hip_runtime.h>

#define B_ 64
#define L_ 512
#define H_ 512
#define CENTER 255

typedef float  f32x4  __attribute__((ext_vector_type(4)));
typedef _Float16 f16x8 __attribute__((ext_vector_type(8)));
typedef unsigned short u16x4 __attribute__((ext_vector_type(4)));
typedef unsigned short u16x8 __attribute__((ext_vector_type(8)));
typedef unsigned short USH;

// ws layout (floats):
//   (free)    [0,      32768)
//   dec_feat [32768,  65536)
//   cov_feat [65536,  98304)
//   spart    [98304,  163840)  float[2][32768]: per-N-half partial scores
//   Bpk     [360448, 491520)   ushort[512][512]: fp16(attn_w) bits (row-major n,k)

__device__ __forceinline__ float fast_tanh(float x) {
    float e = __expf(2.0f * x);
    return 1.0f - 2.0f * __builtin_amdgcn_rcpf(e + 1.0f);
}

// ================= pre v3: ALL roles in 256 blocks, one dispatch round ==================
// (byte-identical to R8 best.)
__launch_bounds__(512)
__global__ void pre_kernel(const float* __restrict__ cvg_w, const float* __restrict__ cvg_b,
                           const float* __restrict__ coverage,
                           const float* __restrict__ aw, USH* __restrict__ bh16,
                           const float* __restrict__ hidden, const float* __restrict__ dec_w,
                           const float* __restrict__ dec_b,
                           float* __restrict__ dec_feat, float* __restrict__ cov_feat) {
    __shared__ float wl2[1024];            // w_eff rows for i0, i1
    __shared__ float cs[512 * 65];         // [j][c] coverage transposed, pad 65
    __shared__ float sbuf[512];
    __shared__ float pr[512];
    const int bid = blockIdx.x, t = threadIdx.x;
    const int i0 = bid, i1 = bid + 256;

    wl2[t]       = cvg_w[((size_t)(i0 * L_ + t)) * H_ + CENTER];
    wl2[512 + t] = cvg_w[((size_t)(i1 * L_ + t)) * H_ + CENTER];

    if (t < 256) {
        int i = bid * 256 + t;
        float4 x = *(const float4*)&aw[(size_t)i * 4];
        float xs[4] = {x.x, x.y, x.z, x.w};
        u16x4 h;
        #pragma unroll
        for (int j = 0; j < 4; ++j)
            h[j] = __builtin_bit_cast(USH, (_Float16)xs[j]);
        *(u16x4*)&bh16[(size_t)i * 4] = h;
    }

    const int b = bid >> 2, qq = bid & 3;
    const int ol = t & 127, part = t >> 7;
    sbuf[t] = hidden[b * H_ + t];
    __syncthreads();

    {
        const float* row  = dec_w + (size_t)(qq * 128 + ol) * H_ + part * 128;
        const float* hseg = sbuf + part * 128;
        float d0 = 0.f, d1 = 0.f, d2 = 0.f, d3 = 0.f;
        #pragma unroll
        for (int k = 0; k < 128; k += 16) {
            float4 w0 = *(const float4*)&row[k];
            float4 w1 = *(const float4*)&row[k + 4];
            float4 w2 = *(const float4*)&row[k + 8];
            float4 w3 = *(const float4*)&row[k + 12];
            d0 += w0.x * hseg[k]      + w0.y * hseg[k + 1]  + w0.z * hseg[k + 2]  + w0.w * hseg[k + 3];
            d1 += w1.x * hseg[k + 4]  + w1.y * hseg[k + 5]  + w1.z * hseg[k + 6]  + w1.w * hseg[k + 7];
            d2 += w2.x * hseg[k + 8]  + w2.y * hseg[k + 9]  + w2.z * hseg[k + 10] + w2.w * hseg[k + 11];
            d3 += w3.x * hseg[k + 12] + w3.y * hseg[k + 13] + w3.z * hseg[k + 14] + w3.w * hseg[k + 15];
        }
        pr[t] = d0 + d1 + d2 + d3;
    }

    #pragma unroll 8
    for (int c = 0; c < 64; ++c)
        cs[t * 65 + c] = coverage[c * L_ + t];
    __syncthreads();

    if (t < 128)
        dec_feat[b * H_ + qq * 128 + t] = pr[t] + pr[t + 128] + pr[t + 256] + pr[t + 384]
                                          + dec_b[qq * 128 + t];

    {
        const int bb = t >> 3, jg = t & 7;
        float s0 = 0.f, s1 = 0.f;
        #pragma unroll 8
        for (int jj = 0; jj < 64; ++jj) {
            int j = jg * 64 + ((jj + jg * 8) & 63);        // rotation: read 2/bank
            float c = cs[j * 65 + bb];
            s0 += c * wl2[j];
            s1 += c * wl2[512 + j];
        }
        s0 += __shfl_xor(s0, 1, 64);
        s0 += __shfl_xor(s0, 2, 64);
        s0 += __shfl_xor(s0, 4, 64);
        s1 += __shfl_xor(s1, 1, 64);
        s1 += __shfl_xor(s1, 2, 64);
        s1 += __shfl_xor(s1, 4, 64);
        if (jg == 0) {
            cov_feat[bb * L_ + i0] = s0 + cvg_b[i0];
            cov_feat[bb * L_ + i1] = s1 + cvg_b[i1];
        }
    }
}

// ================= fused MFMA GEMM (fp16) + tanh + dot(v) -> partial scores =============
// (byte-identical to R8, the 64.7 us best: BN=256 halves, 2 blocks/CU, 8 waves 2Mx4N,
//  B triple-buffered depth-2, A reg-prefetch depth-2 + LDS dbuf, ONE barrier/step,
//  counted vmcnt(4).)
#define BM 128

#define STAGE_B(BUF, KS1)                                                                  \
    {                                                                                      \
        _Pragma("unroll")                                                                  \
        for (int it = 0; it < 2; ++it)                                                     \
            __builtin_amdgcn_global_load_lds(                                              \
                (const __attribute__((address_space(1))) void*)(bh16 + goffB[it] + (KS1) * 32), \
                (__attribute__((address_space(3))) void*)&Bsh[BUF][(wv * 2 + it) * 512],   \
                16, 0, 0);                                                                 \
    }

#define CVTWRITEA2(BUF, A4a, A4b)                                                          \
    {                                                                                      \
        float axs[8] = {A4a.x, A4a.y, A4a.z, A4a.w, A4b.x, A4b.y, A4b.z, A4b.w};           \
        u16x8 hh;                                                                          \
        _Pragma("unroll")                                                                  \
        for (int j = 0; j < 8; ++j)                                                        \
            hh[j] = __builtin_bit_cast(USH, (_Float16)axs[j]);                             \
        *(u16x8*)&Ash[BUF][awoff] = hh;                                                    \
    }

__launch_bounds__(512, 4)
__global__ void fused_score_mfma(const float* __restrict__ enc,
                                 const USH* __restrict__ bh16,
                                 const float* __restrict__ attn_b,
                                 const float* __restrict__ dec_feat,
                                 const float* __restrict__ cov_feat,
                                 const float* __restrict__ v,
                                 float* __restrict__ spart) {
    __shared__ USH Bsh[3][8192];       // [buf][256n x 32k swizzled fp16] = 48 KB
    __shared__ USH Ash[2][4096];       // [buf][128r x 32k swizzled fp16] = 16 KB

    const int t  = threadIdx.x;
    const int wv = t >> 6, ln = t & 63;
    const int wr = wv >> 2, wc = wv & 3;     // 2M x 4N, wave tile 64 x 64
    const int q  = ln >> 4, cl = ln & 15;
    const int mt = blockIdx.x, half = blockIdx.y;
    const int m0 = mt * BM;
    const int b  = mt >> 2;                  // 4 row-tiles per batch row
    const int n0 = half * 256;

    int goffB[2];
    #pragma unroll
    for (int it = 0; it < 2; ++it) {
        int c   = wv * 2 + it;               // 16 chunks cover 256 n
        int srl = ln >> 3;
        int u   = (ln & 7) ^ (srl & 7);
        int n   = n0 + c * 16 + srl * 2 + (u >> 2);
        goffB[it] = n * 512 + (u & 3) * 8;
    }
    const int sA   = (((cl & 1) * 4 + q) ^ ((cl >> 1) & 7)) * 8;
    const int aoff = wr * 2048 + (cl >> 1) * 64 + sA;
    const int boff = wc * 2048 + (cl >> 1) * 64 + sA;

    const int arow = t >> 2, ak4 = t & 3;    // 512 thr: 8 floats (2 float4) per thread
    const int asw  = ((arow & 1) * 4 + ak4) ^ ((arow >> 1) & 7);
    const int awoff = (arow >> 1) * 64 + asw * 8;
    const float* agsrc = enc + (size_t)(m0 + arow) * H_ + ak4 * 8;

    f32x4 acc[4][4];
    #pragma unroll
    for (int mf = 0; mf < 4; ++mf)
        #pragma unroll
        for (int nf = 0; nf < 4; ++nf) acc[mf][nf] = (f32x4){0.f, 0.f, 0.f, 0.f};

    float4 aPa = *(const float4*)(agsrc + 32);
    float4 aPb = *(const float4*)(agsrc + 36);
    float4 c0a = *(const float4*)agsrc;
    float4 c0b = *(const float4*)(agsrc + 4);
    __builtin_amdgcn_sched_barrier(0);
    STAGE_B(0, 0);
    STAGE_B(1, 1);
    __builtin_amdgcn_sched_barrier(0);
    CVTWRITEA2(0, c0a, c0b);
    asm volatile("s_waitcnt lgkmcnt(0)" ::: "memory");
    asm volatile("s_waitcnt vmcnt(2)" ::: "memory");
    __builtin_amdgcn_sched_barrier(0);
    __builtin_amdgcn_s_barrier();

    #pragma unroll
    for (int ks = 0; ks < 16; ++ks) {
        const int curB = ks % 3;
        const int curA = ks & 1, nxtA = curA ^ 1;
        float4 aNa, aNb;
        if (ks < 14) {
            STAGE_B((ks + 2) % 3, ks + 2);
            aNa = *(const float4*)(agsrc + (ks + 2) * 32);
            aNb = *(const float4*)(agsrc + (ks + 2) * 32 + 4);
            __builtin_amdgcn_sched_barrier(0);
        }

        f16x8 ah[4];
        #pragma unroll
        for (int mf = 0; mf < 4; ++mf)
            ah[mf] = *(const f16x8*)&Ash[curA][aoff + mf * 512];
        __builtin_amdgcn_s_setprio(1);
        #pragma unroll
        for (int nf = 0; nf < 4; ++nf) {
            f16x8 bh = *(const f16x8*)&Bsh[curB][boff + nf * 512];
            #pragma unroll
            for (int mf = 0; mf < 4; ++mf)
                acc[mf][nf] = __builtin_amdgcn_mfma_f32_16x16x32_f16(ah[mf], bh, acc[mf][nf], 0, 0, 0);
        }
        __builtin_amdgcn_s_setprio(0);

        if (ks < 15) {
            CVTWRITEA2(nxtA, aPa, aPb);
            aPa = aNa; aPb = aNb;
            asm volatile("s_waitcnt lgkmcnt(0)" ::: "memory");
            if (ks < 14)
                asm volatile("s_waitcnt vmcnt(4)" ::: "memory");
            else
                asm volatile("s_waitcnt vmcnt(0)" ::: "memory");
            __builtin_amdgcn_sched_barrier(0);
            __builtin_amdgcn_s_barrier();
        }
    }
    __syncthreads();

    float (*scred)[BM] = (float (*)[BM])Ash;
    float addv[4], vvv[4];
    #pragma unroll
    for (int nf = 0; nf < 4; ++nf) {
        int n = n0 + wc * 64 + nf * 16 + cl;
        addv[nf] = attn_b[n] + dec_feat[b * H_ + n];
        vvv[nf]  = v[b * H_ + n];
    }
    #pragma unroll
    for (int mf = 0; mf < 4; ++mf) {
        #pragma unroll
        for (int reg = 0; reg < 4; ++reg) {
            int row = wr * 64 + mf * 16 + q * 4 + reg;
            float cf = cov_feat[m0 + row];
            float s = 0.f;
            #pragma unroll
            for (int nf = 0; nf < 4; ++nf)
                s += fast_tanh(acc[mf][nf][reg] + addv[nf] + cf) * vvv[nf];
            s += __shfl_xor(s, 1, 64);
            s += __shfl_xor(s, 2, 64);
            s += __shfl_xor(s, 4, 64);
            s += __shfl_xor(s, 8, 64);
            if (cl == 0) scred[wc][row] = s;
        }
    }
    __syncthreads();
    if (t < BM) {
        float s = 0.f;
        #pragma unroll
        for (int g = 0; g < 4; ++g) s += scred[g][t];
        spart[half * (B_ * L_) + m0 + t] = s;
    }
}

// ================= smctx: masked softmax + outputs + context ============================
// (R8 + two-level final reduce: 128 threads x 8 partials -> 32 threads x 4.)
__launch_bounds__(1024)
__global__ void smctx_kernel(const float* __restrict__ spart, const int* __restrict__ mask,
                             const float* __restrict__ coverage, const float* __restrict__ enc,
                             float* __restrict__ out) {
    __shared__ float w[512];
    __shared__ float red[16];
    __shared__ float red2[16];
    __shared__ float4 cred4[32][32];   // 16 KB
    __shared__ float4 cmid[4][32];     // 2 KB (level-1 partials)
    const int bid = blockIdx.x, b = bid >> 2, hc = bid & 3, t = threadIdx.x;
    const int wv = t >> 6, ln = t & 63;

    float sv = 0.f; bool mk = false;
    if (t < 512) {
        mk = (mask[b * L_ + t] == 1);
        sv = spart[b * L_ + t] + spart[B_ * L_ + b * L_ + t];
    }
    float val = (t < 512 && mk) ? sv : -INFINITY;

    float r = val;
    #pragma unroll
    for (int d = 1; d <= 32; d <<= 1) r = fmaxf(r, __shfl_xor(r, d, 64));
    if (ln == 0) red[wv] = r;
    __syncthreads();
    float gmax = red[0];
    #pragma unroll
    for (int i = 1; i < 16; ++i) gmax = fmaxf(gmax, red[i]);

    float p = (t < 512 && mk) ? __expf(sv - gmax) : 0.f;
    float qq = p;
    #pragma unroll
    for (int d = 1; d <= 32; d <<= 1) qq += __shfl_xor(qq, d, 64);
    if (ln == 0) red2[wv] = qq;
    __syncthreads();
    float tot = 0.f;
    #pragma unroll
    for (int i = 0; i < 16; ++i) tot += red2[i];

    float wt = p / tot;
    if (t < 512) {
        w[t] = wt;
        if (hc == 0) {
            out[B_ * H_ + b * L_ + t] = wt;                                   // attn_weights
            out[B_ * H_ + B_ * L_ + b * L_ + t] = coverage[b * L_ + t] + wt;  // new_coverage
        }
    }
    __syncthreads();

    const int c4 = t & 31, rg = t >> 5;    // 32 row-groups x 32 float4 columns
    const float4* ebase = (const float4*)enc
                          + ((size_t)(b * L_ + rg)) * 128 + hc * 32 + c4;
    float4 a4 = {0.f, 0.f, 0.f, 0.f};
    #pragma unroll
    for (int k = 0; k < 16; ++k) {         // rows rg, rg+32, ..., rg+480
        float wl_ = w[rg + 32 * k];
        float4 e = ebase[(size_t)(32 * k) * 128];
        a4.x += wl_ * e.x; a4.y += wl_ * e.y; a4.z += wl_ * e.z; a4.w += wl_ * e.w;
    }
    cred4[rg][c4] = a4;
    __syncthreads();
    if (t < 128) {
        const int gq = t >> 5;             // level 1: 4 quarters x 32 cols, 8 adds each
        float4 s = {0.f, 0.f, 0.f, 0.f};
        #pragma unroll
        for (int g = 0; g < 8; ++g) {
            float4 c = cred4[gq * 8 + g][c4];
            s.x += c.x; s.y += c.y; s.z += c.z; s.w += c.w;
        }
        cmid[gq][c4] = s;
    }
    __syncthreads();
    if (t < 32) {                          // level 2: 4 adds
        float4 s = {0.f, 0.f, 0.f, 0.f};
        #pragma unroll
        for (int g = 0; g < 4; ++g) {
            float4 c = cmid[g][t];
            s.x += c.x; s.y += c.y; s.z += c.z; s.w += c.w;
        }
        *(float4*)&out[b * H_ + hc * 128 + t * 4] = s;
    }
}

extern "C" void kernel_launch(void* const* d_in, const int* in_sizes, int n_in,
                              void* d_out, int out_size, void* d_ws, size_t ws_size,
                              hipStream_t stream) {
    const float* enc      = (const float*)d_in[0];
    const int*   mask     = (const int*)d_in[1];
    const float* hidden   = (const float*)d_in[2];
    const float* coverage = (const float*)d_in[3];
    const float* attn_w   = (const float*)d_in[4];
    const float* attn_b   = (const float*)d_in[5];
    const float* dec_w    = (const float*)d_in[6];
    const float* dec_b    = (const float*)d_in[7];
    const float* cvg_w    = (const float*)d_in[8];
    const float* cvg_b    = (const float*)d_in[9];
    const float* v        = (const float*)d_in[10];
    float* out = (float*)d_out;
    float* ws  = (float*)d_ws;
    float* dec_feat = ws + 32768;
    float* cov_feat = ws + 65536;
    float* spart    = ws + 98304;
    USH* bpk = (USH*)(ws + 360448);

    hipLaunchKernelGGL(pre_kernel,       dim3(256),     dim3(512),  0, stream,
                       cvg_w, cvg_b, coverage, attn_w, bpk, hidden, dec_w, dec_b,
                       dec_feat, cov_feat);
    hipLaunchKernelGGL(fused_score_mfma, dim3(256, 2),  dim3(512),  0, stream,
                       enc, bpk, attn_b, dec_feat, cov_feat, v, spart);
    hipLaunchKernelGGL(smctx_kernel,     dim3(256),     dim3(1024), 0, stream,
                       spart, mask, coverage, enc, out);
}